// Round 1
// baseline (2228.853 us; speedup 1.0000x reference)
//
#include <hip/hip_runtime.h>

#define NN 100000
#define NE 3200000
#define NCHUNK 49   // ceil(NN / 2048)

// ---------------- degrees / norms ----------------
__global__ void k_init_deg(int* __restrict__ dego, int* __restrict__ degi){
  int i = blockIdx.x*256 + threadIdx.x;
  if(i < NN){ dego[i]=1; degi[i]=1; }   // self-loop included
}

__global__ void k_hist(const int* __restrict__ src, const int* __restrict__ dst,
                       int* __restrict__ dego, int* __restrict__ degi){
  int stride = gridDim.x*blockDim.x;
  for(int e = blockIdx.x*blockDim.x + threadIdx.x; e < NE; e += stride){
    atomicAdd(&dego[src[e]], 1);
    atomicAdd(&degi[dst[e]], 1);
  }
}

__global__ void k_norm(const int* __restrict__ dego, const int* __restrict__ degi,
                       float* __restrict__ ns, float* __restrict__ nd){
  int i = blockIdx.x*256 + threadIdx.x;
  if(i < NN){ ns[i] = rsqrtf((float)dego[i]); nd[i] = rsqrtf((float)degi[i]); }
}

// ---------------- scan for CSR row_ptr (counts = degi-1, self-loop excluded) ---------
__global__ void k_scan1(const int* __restrict__ degi, int* __restrict__ texcl,
                        int* __restrict__ partial){
  __shared__ int s[256];
  int b = blockIdx.x, t = threadIdx.x;
  int base = b*2048 + t*8;
  int sum = 0;
  #pragma unroll
  for(int j=0;j<8;j++){ int v = base+j; if(v<NN) sum += degi[v]-1; }
  s[t] = sum; __syncthreads();
  for(int off=1; off<256; off<<=1){
    int v = (t>=off) ? s[t-off] : 0;
    __syncthreads();
    s[t] += v;
    __syncthreads();
  }
  texcl[b*256+t] = s[t] - sum;
  if(t==255) partial[b] = s[255];
}

__global__ void k_scan2(const int* __restrict__ partial, int* __restrict__ coff){
  if(threadIdx.x==0){
    int run=0;
    for(int i=0;i<NCHUNK;i++){ coff[i]=run; run+=partial[i]; }
  }
}

__global__ void k_scan3(const int* __restrict__ degi, const int* __restrict__ texcl,
                        const int* __restrict__ coff, int* __restrict__ rowp,
                        int* __restrict__ fill){
  int b = blockIdx.x, t = threadIdx.x;
  int base = b*2048 + t*8;
  int run = coff[b] + texcl[b*256+t];
  #pragma unroll
  for(int j=0;j<8;j++){
    int v = base+j;
    if(v<NN){ rowp[v]=run; fill[v]=0; run += degi[v]-1; }
  }
}

__global__ void k_fill(const int* __restrict__ src, const int* __restrict__ dst,
                       const int* __restrict__ rowp, int* __restrict__ fill,
                       int* __restrict__ csr){
  int stride = gridDim.x*blockDim.x;
  for(int e = blockIdx.x*blockDim.x + threadIdx.x; e < NE; e += stride){
    int v = dst[e];
    int pos = rowp[v] + atomicAdd(&fill[v], 1);
    csr[pos] = src[e];
  }
}

// ---------------- SpMM: one wave per destination node ----------------
template<int DIM>
struct alignas(sizeof(float)*(DIM/64)) FVec { float v[DIM/64]; };

template<int DIM>
__global__ void k_spmm(const float* __restrict__ h, const int* __restrict__ rowp,
                       const int* __restrict__ degi, const int* __restrict__ csr,
                       const float* __restrict__ ns, const float* __restrict__ nd,
                       float* __restrict__ out){
  constexpr int VEC = DIM/64;
  int w = (blockIdx.x*blockDim.x + threadIdx.x) >> 6;
  int lane = threadIdx.x & 63;
  if(w >= NN) return;
  float acc[VEC];
  {
    float nsv = ns[w];
    FVec<DIM> x = *(reinterpret_cast<const FVec<DIM>*>(h + (size_t)w*DIM) + lane);
    #pragma unroll
    for(int i=0;i<VEC;i++) acc[i] = x.v[i]*nsv;   // self-loop term
  }
  int start = rowp[w];
  int cnt = degi[w]-1;
  for(int j=0;j<cnt;j++){
    int u = csr[start+j];
    float nu = ns[u];
    FVec<DIM> x = *(reinterpret_cast<const FVec<DIM>*>(h + (size_t)u*DIM) + lane);
    #pragma unroll
    for(int i=0;i<VEC;i++) acc[i] += x.v[i]*nu;
  }
  float ndv = nd[w];
  float* o = out + (size_t)w*DIM + lane*VEC;
  #pragma unroll
  for(int i=0;i<VEC;i++) o[i] = acc[i]*ndv;
}

// ---------------- fp32 GEMM: C = relu(A@W + b), 128x128 tile, 8x8 microtile ---------
template<bool RELU>
__global__ __launch_bounds__(256) void k_gemm(const float* __restrict__ A,
                       const float* __restrict__ W, const float* __restrict__ bias,
                       float* __restrict__ C, int M, int K, int Nn){
  __shared__ float As[16][128];   // transposed A tile
  __shared__ float Bs[16][128];
  int t = threadIdx.x;
  int tx = t & 15, ty = t >> 4;
  int row0 = blockIdx.y*128, col0 = blockIdx.x*128;
  float acc[8][8];
  #pragma unroll
  for(int i=0;i<8;i++)
    #pragma unroll
    for(int j=0;j<8;j++) acc[i][j]=0.f;
  float bv[8];
  #pragma unroll
  for(int j=0;j<8;j++){ int gc=col0+tx*8+j; bv[j] = (gc<Nn)? bias[gc] : 0.f; }

  int ar_ = t>>1, ak_ = (t&1)*8;     // A-tile: row ar_ (0..127), k-offset ak_ (0/8)
  int brk = t>>4, bcc = (t&15)*8;    // B-tile: k-row brk (0..15), col bcc

  for(int k0=0;k0<K;k0+=16){
    {
      int grow = row0 + ar_;
      float4 a0, a1;
      if(grow < M){
        const float* p = A + (size_t)grow*K + k0 + ak_;
        a0 = *(const float4*)p; a1 = *(const float4*)(p+4);
      } else { a0 = make_float4(0,0,0,0); a1 = a0; }
      As[ak_+0][ar_]=a0.x; As[ak_+1][ar_]=a0.y; As[ak_+2][ar_]=a0.z; As[ak_+3][ar_]=a0.w;
      As[ak_+4][ar_]=a1.x; As[ak_+5][ar_]=a1.y; As[ak_+6][ar_]=a1.z; As[ak_+7][ar_]=a1.w;
    }
    {
      const float* p = W + (size_t)(k0+brk)*Nn;
      #pragma unroll
      for(int h4=0; h4<2; h4++){
        int gc = col0 + bcc + h4*4;
        float4 b4;
        if(gc+3 < Nn){ b4 = *(const float4*)(p+gc); }
        else {
          b4.x = (gc+0<Nn)? p[gc+0]:0.f; b4.y = (gc+1<Nn)? p[gc+1]:0.f;
          b4.z = (gc+2<Nn)? p[gc+2]:0.f; b4.w = (gc+3<Nn)? p[gc+3]:0.f;
        }
        Bs[brk][bcc+h4*4+0]=b4.x; Bs[brk][bcc+h4*4+1]=b4.y;
        Bs[brk][bcc+h4*4+2]=b4.z; Bs[brk][bcc+h4*4+3]=b4.w;
      }
    }
    __syncthreads();
    #pragma unroll
    for(int k=0;k<16;k++){
      float ar[8], br[8];
      *(float4*)&ar[0] = *(const float4*)&As[k][ty*8];
      *(float4*)&ar[4] = *(const float4*)&As[k][ty*8+4];
      *(float4*)&br[0] = *(const float4*)&Bs[k][tx*8];
      *(float4*)&br[4] = *(const float4*)&Bs[k][tx*8+4];
      #pragma unroll
      for(int i=0;i<8;i++)
        #pragma unroll
        for(int j=0;j<8;j++) acc[i][j] += ar[i]*br[j];
    }
    __syncthreads();
  }
  #pragma unroll
  for(int i=0;i<8;i++){
    int grow = row0 + ty*8 + i;
    if(grow >= M) continue;
    float* cp = C + (size_t)grow*Nn;
    #pragma unroll
    for(int jj=0;jj<8;jj+=4){
      int gc = col0 + tx*8 + jj;
      float4 v;
      v.x = acc[i][jj+0]+bv[jj+0]; v.y = acc[i][jj+1]+bv[jj+1];
      v.z = acc[i][jj+2]+bv[jj+2]; v.w = acc[i][jj+3]+bv[jj+3];
      if(RELU){
        v.x=fmaxf(v.x,0.f); v.y=fmaxf(v.y,0.f); v.z=fmaxf(v.z,0.f); v.w=fmaxf(v.w,0.f);
      }
      if(gc+3 < Nn){ *(float4*)(cp+gc) = v; }
      else {
        if(gc+0<Nn) cp[gc+0]=v.x; if(gc+1<Nn) cp[gc+1]=v.y;
        if(gc+2<Nn) cp[gc+2]=v.z; if(gc+3<Nn) cp[gc+3]=v.w;
      }
    }
  }
}

// ---------------- batchnorm stats + fused final linear ----------------
__global__ void k_bn0(float* __restrict__ s, float* __restrict__ q){
  int t = threadIdx.x;
  if(t<200){ s[t]=0.f; q[t]=0.f; }
}

__global__ void k_bn1(const float* __restrict__ z, float* __restrict__ bns,
                      float* __restrict__ bnq){
  int lane = threadIdx.x & 63;
  int gw = (blockIdx.x*blockDim.x + threadIdx.x) >> 6;
  int nw = (gridDim.x*blockDim.x) >> 6;
  float s[4]={0,0,0,0}, q[4]={0,0,0,0};
  for(int r=gw; r<NN; r+=nw){
    const float* zr = z + (size_t)r*200;
    #pragma unroll
    for(int i=0;i<4;i++){
      int c = lane + i*64;
      if(c<200){ float x=zr[c]; s[i]+=x; q[i]+=x*x; }
    }
  }
  #pragma unroll
  for(int i=0;i<4;i++){
    int c = lane + i*64;
    if(c<200){ atomicAdd(&bns[c], s[i]); atomicAdd(&bnq[c], q[i]); }
  }
}

__global__ void k_bn2(const float* __restrict__ bns, const float* __restrict__ bnq,
                      const float* __restrict__ gamma, const float* __restrict__ beta,
                      const float* __restrict__ Wm2, const float* __restrict__ bm2,
                      float* __restrict__ w2a, float* __restrict__ cc2){
  __shared__ float c0s[200];
  int t = threadIdx.x;
  if(t<200){
    float mu  = bns[t] * (1.0f/NN);
    float var = bnq[t] * (1.0f/NN) - mu*mu;
    float a   = rsqrtf(var + 1e-5f) * gamma[t];
    w2a[t*2+0] = a*Wm2[t*2+0];
    w2a[t*2+1] = a*Wm2[t*2+1];
    c0s[t] = beta[t] - mu*a;
  }
  __syncthreads();
  if(t<2){
    float cst = bm2[t];
    for(int k=0;k<200;k++) cst += c0s[k]*Wm2[k*2+t];
    cc2[t] = cst;
  }
}

__global__ void k_final(const float* __restrict__ z, const float* __restrict__ w2a,
                        const float* __restrict__ cc2, float* __restrict__ out){
  int lane = threadIdx.x & 63;
  int gw = (blockIdx.x*blockDim.x + threadIdx.x) >> 6;
  if(gw >= NN) return;
  const float* zr = z + (size_t)gw*200;
  float p0=0.f, p1=0.f;
  #pragma unroll
  for(int i=0;i<4;i++){
    int c = lane + i*64;
    if(c<200){ float x=zr[c]; p0 += x*w2a[c*2+0]; p1 += x*w2a[c*2+1]; }
  }
  for(int off=32; off>0; off>>=1){
    p0 += __shfl_down(p0, off);
    p1 += __shfl_down(p1, off);
  }
  if(lane==0){ out[gw*2+0] = p0 + cc2[0]; out[gw*2+1] = p1 + cc2[1]; }
}

// ---------------- launch ----------------
extern "C" void kernel_launch(void* const* d_in, const int* in_sizes, int n_in,
                              void* d_out, int out_size, void* d_ws, size_t ws_size,
                              hipStream_t stream) {
  const float* features = (const float*)d_in[0];
  const int*   src = (const int*)d_in[1];
  const int*   dst = (const int*)d_in[2];
  const float* W0  = (const float*)d_in[3];
  const float* b0  = (const float*)d_in[4];
  const float* W1  = (const float*)d_in[5];
  const float* b1  = (const float*)d_in[6];
  const float* W2  = (const float*)d_in[7];
  const float* b2  = (const float*)d_in[8];
  const float* Wm1 = (const float*)d_in[9];
  const float* bm1 = (const float*)d_in[10];
  const float* gamma = (const float*)d_in[11];
  const float* beta  = (const float*)d_in[12];
  const float* Wm2 = (const float*)d_in[13];
  const float* bm2 = (const float*)d_in[14];
  float* out = (float*)d_out;

  char* p = (char*)d_ws;
  auto alloc = [&](size_t bytes)->void*{
    void* r = (void*)p; p += (bytes + 255) & ~(size_t)255; return r;
  };
  float* bufA = (float*)alloc((size_t)NN*256*4);
  float* bufB = (float*)alloc((size_t)NN*256*4);
  int*   csr  = (int*)alloc((size_t)NE*4);
  int*   rowp = (int*)alloc((size_t)(NN+1)*4);
  int*   fill = (int*)alloc((size_t)NN*4);
  int*   dego = (int*)alloc((size_t)NN*4);
  int*   degi = (int*)alloc((size_t)NN*4);
  float* ns   = (float*)alloc((size_t)NN*4);
  float* nd   = (float*)alloc((size_t)NN*4);
  int*   texcl= (int*)alloc((size_t)NCHUNK*256*4);
  int*   partial = (int*)alloc((size_t)NCHUNK*4);
  int*   coff    = (int*)alloc((size_t)NCHUNK*4);
  float* bns  = (float*)alloc(200*4);
  float* bnq  = (float*)alloc(200*4);
  float* w2a  = (float*)alloc(400*4);
  float* cc2  = (float*)alloc(2*4);

  int nblk = (NN + 255)/256;
  k_init_deg<<<nblk, 256, 0, stream>>>(dego, degi);
  k_hist<<<2048, 256, 0, stream>>>(src, dst, dego, degi);
  k_norm<<<nblk, 256, 0, stream>>>(dego, degi, ns, nd);
  k_scan1<<<NCHUNK, 256, 0, stream>>>(degi, texcl, partial);
  k_scan2<<<1, 64, 0, stream>>>(partial, coff);
  k_scan3<<<NCHUNK, 256, 0, stream>>>(degi, texcl, coff, rowp, fill);
  k_fill<<<2048, 256, 0, stream>>>(src, dst, rowp, fill, csr);

  int sblk = (NN + 3)/4;   // 4 waves per 256-thread block, 1 wave per node
  // layer 0: dim 128
  k_spmm<128><<<sblk, 256, 0, stream>>>(features, rowp, degi, csr, ns, nd, bufA);
  k_gemm<true><<<dim3(1, (NN+127)/128), 256, 0, stream>>>(bufA, W0, b0, bufB, NN, 128, 128);
  // layer 1: agg dim 128 -> out 256
  k_spmm<128><<<sblk, 256, 0, stream>>>(bufB, rowp, degi, csr, ns, nd, bufA);
  k_gemm<true><<<dim3(2, (NN+127)/128), 256, 0, stream>>>(bufA, W1, b1, bufB, NN, 128, 256);
  // layer 2: dim 256
  k_spmm<256><<<sblk, 256, 0, stream>>>(bufB, rowp, degi, csr, ns, nd, bufA);
  k_gemm<true><<<dim3(2, (NN+127)/128), 256, 0, stream>>>(bufA, W2, b2, bufB, NN, 256, 256);
  // MLP hidden: z = relu(h3 @ Wm1 + bm1), 256 -> 200
  k_gemm<true><<<dim3(2, (NN+127)/128), 256, 0, stream>>>(bufB, Wm1, bm1, bufA, NN, 256, 200);
  // batchnorm stats + fused final linear
  k_bn0<<<1, 256, 0, stream>>>(bns, bnq);
  k_bn1<<<1024, 256, 0, stream>>>(bufA, bns, bnq);
  k_bn2<<<1, 256, 0, stream>>>(bns, bnq, gamma, beta, Wm2, bm2, w2a, cc2);
  k_final<<<sblk, 256, 0, stream>>>(bufA, w2a, cc2, out);
}

// Round 2
// 1722.319 us; speedup vs baseline: 1.2941x; 1.2941x over previous
//
#include <hip/hip_runtime.h>

#define NN 100000
#define NE 3200000
#define NCHUNK 49   // ceil(NN / 2048)

typedef unsigned short u16;
typedef unsigned int u32;
typedef __attribute__((ext_vector_type(8))) short short8v;
typedef __attribute__((ext_vector_type(4))) float f32x4;

__device__ __forceinline__ u16 f2b(float f){
  u32 u = __float_as_uint(f);
  u32 r = (u + 0x7fffu + ((u >> 16) & 1u)) >> 16;
  return (u16)r;
}
__device__ __forceinline__ float b2f(u16 b){
  return __uint_as_float(((u32)b) << 16);
}

// ---------------- degrees / norms ----------------
__global__ void k_init_deg(int* __restrict__ dego, int* __restrict__ degi){
  int i = blockIdx.x*256 + threadIdx.x;
  if(i < NN){ dego[i]=1; degi[i]=1; }   // self-loop included
}

__global__ void k_hist(const int* __restrict__ src, const int* __restrict__ dst,
                       int* __restrict__ dego, int* __restrict__ degi){
  int stride = gridDim.x*blockDim.x;
  for(int e = blockIdx.x*blockDim.x + threadIdx.x; e < NE; e += stride){
    atomicAdd(&dego[src[e]], 1);
    atomicAdd(&degi[dst[e]], 1);
  }
}

__global__ void k_norm(const int* __restrict__ dego, const int* __restrict__ degi,
                       float* __restrict__ ns, float* __restrict__ nd){
  int i = blockIdx.x*256 + threadIdx.x;
  if(i < NN){ ns[i] = rsqrtf((float)dego[i]); nd[i] = rsqrtf((float)degi[i]); }
}

// ---------------- scan for CSR row_ptr ----------------
__global__ void k_scan1(const int* __restrict__ degi, int* __restrict__ texcl,
                        int* __restrict__ partial){
  __shared__ int s[256];
  int b = blockIdx.x, t = threadIdx.x;
  int base = b*2048 + t*8;
  int sum = 0;
  #pragma unroll
  for(int j=0;j<8;j++){ int v = base+j; if(v<NN) sum += degi[v]-1; }
  s[t] = sum; __syncthreads();
  for(int off=1; off<256; off<<=1){
    int v = (t>=off) ? s[t-off] : 0;
    __syncthreads();
    s[t] += v;
    __syncthreads();
  }
  texcl[b*256+t] = s[t] - sum;
  if(t==255) partial[b] = s[255];
}

__global__ void k_scan2(const int* __restrict__ partial, int* __restrict__ coff){
  if(threadIdx.x==0){
    int run=0;
    for(int i=0;i<NCHUNK;i++){ coff[i]=run; run+=partial[i]; }
  }
}

__global__ void k_scan3(const int* __restrict__ degi, const int* __restrict__ texcl,
                        const int* __restrict__ coff, int* __restrict__ rowp,
                        int* __restrict__ fill){
  int b = blockIdx.x, t = threadIdx.x;
  int base = b*2048 + t*8;
  int run = coff[b] + texcl[b*256+t];
  #pragma unroll
  for(int j=0;j<8;j++){
    int v = base+j;
    if(v<NN){ rowp[v]=run; fill[v]=0; run += degi[v]-1; }
  }
}

__global__ void k_fill(const int* __restrict__ src, const int* __restrict__ dst,
                       const int* __restrict__ rowp, int* __restrict__ fill,
                       int* __restrict__ csr){
  int stride = gridDim.x*blockDim.x;
  for(int e = blockIdx.x*blockDim.x + threadIdx.x; e < NE; e += stride){
    int v = dst[e];
    int pos = rowp[v] + atomicAdd(&fill[v], 1);
    csr[pos] = src[e];
  }
}

// ---------------- convert features*ns -> bf16 ----------------
__global__ void k_cvt(const float* __restrict__ f, const float* __restrict__ ns,
                      u16* __restrict__ out){
  int i = blockIdx.x*256 + threadIdx.x;    // groups of 4 elems, 32 groups/row
  if(i >= NN*32) return;
  int row = i >> 5;
  float nsv = ns[row];
  float4 v = *(const float4*)(f + (size_t)i*4);
  u32 w0 = (u32)f2b(v.x*nsv) | ((u32)f2b(v.y*nsv) << 16);
  u32 w1 = (u32)f2b(v.z*nsv) | ((u32)f2b(v.w*nsv) << 16);
  *(uint2*)(out + (size_t)i*4) = make_uint2(w0, w1);
}

// ---------------- transpose weight -> bf16 N x K ----------------
__global__ void k_transposew(const float* __restrict__ W, u16* __restrict__ Wt,
                             int K, int N){
  int n = blockIdx.x*16 + threadIdx.x;
  int k = blockIdx.y*16 + threadIdx.y;
  if(n < N && k < K) Wt[(size_t)n*K + k] = f2b(W[(size_t)k*N + n]);
}

// ---------------- SpMM (bf16 gather, fp32 accum, bf16 out*nd) ----------------
template<int DIM>
__global__ void k_spmm_b(const u16* __restrict__ h, const int* __restrict__ rowp,
                         const int* __restrict__ degi, const int* __restrict__ csr,
                         const float* __restrict__ nd, u16* __restrict__ out){
  constexpr int V = DIM/64;      // 2 or 4 bf16 per lane
  constexpr int W_ = V/2;        // u32 words per lane
  int w = (blockIdx.x*blockDim.x + threadIdx.x) >> 6;
  int lane = threadIdx.x & 63;
  if(w >= NN) return;
  const u32* hw = (const u32*)h;
  float acc[V];
  #pragma unroll
  for(int i=0;i<W_;i++){
    u32 v = hw[(size_t)w*(DIM/2) + lane*W_ + i];     // self term (h premul ns)
    acc[2*i]   = b2f((u16)(v & 0xffff));
    acc[2*i+1] = b2f((u16)(v >> 16));
  }
  int start = rowp[w];
  int cnt = degi[w]-1;
  for(int j=0;j<cnt;j++){
    int u = csr[start+j];
    #pragma unroll
    for(int i=0;i<W_;i++){
      u32 v = hw[(size_t)u*(DIM/2) + lane*W_ + i];
      acc[2*i]   += b2f((u16)(v & 0xffff));
      acc[2*i+1] += b2f((u16)(v >> 16));
    }
  }
  float ndv = nd[w];
  u32* ow = (u32*)out;
  #pragma unroll
  for(int i=0;i<W_;i++){
    u32 lo = f2b(acc[2*i]*ndv);
    u32 hi = f2b(acc[2*i+1]*ndv);
    ow[(size_t)w*(DIM/2) + lane*W_ + i] = lo | (hi << 16);
  }
}

// ---------------- bf16 MFMA GEMM: out = relu(A @ Wt^T + bias) ----------------
// A: M x K bf16 row-major. Bt: N x K bf16 row-major (= W^T). fp32 accum.
// OUTMODE 0: bf16 out * ns[row]; 1: bf16 out; 2: fp32 out.
template<int OUTMODE>
__global__ __launch_bounds__(256) void k_gemm_mfma(
    const u16* __restrict__ A, const u16* __restrict__ Bt,
    const float* __restrict__ bias, const float* __restrict__ ns,
    u16* __restrict__ outb, float* __restrict__ outf,
    int M, int K, int Nn)
{
  __shared__ u16 As[128*32];
  __shared__ u16 Bs[128*32];
  int t = threadIdx.x;
  int wave = t >> 6, lane = t & 63;
  int l15 = lane & 15, l4 = lane >> 4;
  int wr = (wave >> 1)*64, wc = (wave & 1)*64;
  int row0 = blockIdx.y*128, col0 = blockIdx.x*128;

  f32x4 acc[4][4];
  #pragma unroll
  for(int m=0;m<4;m++)
    #pragma unroll
    for(int n=0;n<4;n++) acc[m][n] = (f32x4)(0.f);

  // staging: thread t -> row st_r (2 threads/row), 16 elems each (2x 16B chunks)
  int st_r = t >> 1;
  int kc0 = (t & 1)*2;                 // linear chunk index 0 or 2
  int sw  = (st_r >> 1) & 3;           // XOR swizzle (T2): 2-way max conflict
  int c0 = kc0 ^ sw, c1 = (kc0+1) ^ sw;
  bool avalid = (row0 + st_r) < M;
  bool bvalid = (col0 + st_r) < Nn;
  const u16* Ap = A  + (size_t)(row0 + st_r)*K + kc0*8;
  const u16* Bp = Bt + (size_t)(col0 + st_r)*K + kc0*8;

  for(int k0 = 0; k0 < K; k0 += 32){
    uint4 va0 = make_uint4(0,0,0,0), va1 = va0, vb0 = va0, vb1 = va0;
    if(avalid){ va0 = *(const uint4*)(Ap + k0); va1 = *(const uint4*)(Ap + k0 + 8); }
    if(bvalid){ vb0 = *(const uint4*)(Bp + k0); vb1 = *(const uint4*)(Bp + k0 + 8); }
    __syncthreads();
    *(uint4*)&As[st_r*32 + c0*8] = va0;
    *(uint4*)&As[st_r*32 + c1*8] = va1;
    *(uint4*)&Bs[st_r*32 + c0*8] = vb0;
    *(uint4*)&Bs[st_r*32 + c1*8] = vb1;
    __syncthreads();

    short8v af[4], bg[4];
    #pragma unroll
    for(int m=0;m<4;m++){
      int r = wr + m*16 + l15;
      int kc = l4 ^ ((r >> 1) & 3);
      af[m] = *(const short8v*)&As[r*32 + kc*8];
    }
    #pragma unroll
    for(int n=0;n<4;n++){
      int r = wc + n*16 + l15;
      int kc = l4 ^ ((r >> 1) & 3);
      bg[n] = *(const short8v*)&Bs[r*32 + kc*8];
    }
    #pragma unroll
    for(int m=0;m<4;m++)
      #pragma unroll
      for(int n=0;n<4;n++)
        acc[m][n] = __builtin_amdgcn_mfma_f32_16x16x32_bf16(af[m], bg[n], acc[m][n], 0, 0, 0);
    __syncthreads();
  }

  float nsv[4][4];
  if(OUTMODE == 0){
    #pragma unroll
    for(int m=0;m<4;m++)
      #pragma unroll
      for(int r=0;r<4;r++){
        int gr = row0 + wr + m*16 + l4*4 + r;
        nsv[m][r] = (gr < M) ? ns[gr] : 0.f;
      }
  }
  #pragma unroll
  for(int n=0;n<4;n++){
    int gc = col0 + wc + n*16 + l15;
    float bv = (gc < Nn) ? bias[gc] : 0.f;
    #pragma unroll
    for(int m=0;m<4;m++){
      #pragma unroll
      for(int r=0;r<4;r++){
        int gr = row0 + wr + m*16 + l4*4 + r;
        if(gr >= M || gc >= Nn) continue;
        float v = fmaxf(acc[m][n][r] + bv, 0.f);
        if(OUTMODE == 0)      outb[(size_t)gr*Nn + gc] = f2b(v * nsv[m][r]);
        else if(OUTMODE == 1) outb[(size_t)gr*Nn + gc] = f2b(v);
        else                  outf[(size_t)gr*Nn + gc] = v;
      }
    }
  }
}

// ---------------- batchnorm stats + fused final linear ----------------
__global__ void k_bn0(float* __restrict__ s, float* __restrict__ q){
  int t = threadIdx.x;
  if(t<200){ s[t]=0.f; q[t]=0.f; }
}

__global__ void k_bn1(const float* __restrict__ z, float* __restrict__ bns,
                      float* __restrict__ bnq){
  int lane = threadIdx.x & 63;
  int gw = (blockIdx.x*blockDim.x + threadIdx.x) >> 6;
  int nw = (gridDim.x*blockDim.x) >> 6;
  float s[4]={0,0,0,0}, q[4]={0,0,0,0};
  for(int r=gw; r<NN; r+=nw){
    const float* zr = z + (size_t)r*200;
    #pragma unroll
    for(int i=0;i<4;i++){
      int c = lane + i*64;
      if(c<200){ float x=zr[c]; s[i]+=x; q[i]+=x*x; }
    }
  }
  #pragma unroll
  for(int i=0;i<4;i++){
    int c = lane + i*64;
    if(c<200){ atomicAdd(&bns[c], s[i]); atomicAdd(&bnq[c], q[i]); }
  }
}

__global__ void k_bn2(const float* __restrict__ bns, const float* __restrict__ bnq,
                      const float* __restrict__ gamma, const float* __restrict__ beta,
                      const float* __restrict__ Wm2, const float* __restrict__ bm2,
                      float* __restrict__ w2a, float* __restrict__ cc2){
  __shared__ float c0s[200];
  int t = threadIdx.x;
  if(t<200){
    float mu  = bns[t] * (1.0f/NN);
    float var = bnq[t] * (1.0f/NN) - mu*mu;
    float a   = rsqrtf(var + 1e-5f) * gamma[t];
    w2a[t*2+0] = a*Wm2[t*2+0];
    w2a[t*2+1] = a*Wm2[t*2+1];
    c0s[t] = beta[t] - mu*a;
  }
  __syncthreads();
  if(t<2){
    float cst = bm2[t];
    for(int k=0;k<200;k++) cst += c0s[k]*Wm2[k*2+t];
    cc2[t] = cst;
  }
}

__global__ void k_final(const float* __restrict__ z, const float* __restrict__ w2a,
                        const float* __restrict__ cc2, float* __restrict__ out){
  int lane = threadIdx.x & 63;
  int gw = (blockIdx.x*blockDim.x + threadIdx.x) >> 6;
  if(gw >= NN) return;
  const float* zr = z + (size_t)gw*200;
  float p0=0.f, p1=0.f;
  #pragma unroll
  for(int i=0;i<4;i++){
    int c = lane + i*64;
    if(c<200){ float x=zr[c]; p0 += x*w2a[c*2+0]; p1 += x*w2a[c*2+1]; }
  }
  for(int off=32; off>0; off>>=1){
    p0 += __shfl_down(p0, off);
    p1 += __shfl_down(p1, off);
  }
  if(lane==0){ out[gw*2+0] = p0 + cc2[0]; out[gw*2+1] = p1 + cc2[1]; }
}

// ---------------- launch ----------------
extern "C" void kernel_launch(void* const* d_in, const int* in_sizes, int n_in,
                              void* d_out, int out_size, void* d_ws, size_t ws_size,
                              hipStream_t stream) {
  const float* features = (const float*)d_in[0];
  const int*   src = (const int*)d_in[1];
  const int*   dst = (const int*)d_in[2];
  const float* W0  = (const float*)d_in[3];
  const float* b0  = (const float*)d_in[4];
  const float* W1  = (const float*)d_in[5];
  const float* b1  = (const float*)d_in[6];
  const float* W2  = (const float*)d_in[7];
  const float* b2  = (const float*)d_in[8];
  const float* Wm1 = (const float*)d_in[9];
  const float* bm1 = (const float*)d_in[10];
  const float* gamma = (const float*)d_in[11];
  const float* beta  = (const float*)d_in[12];
  const float* Wm2 = (const float*)d_in[13];
  const float* bm2 = (const float*)d_in[14];
  float* out = (float*)d_out;

  char* p = (char*)d_ws;
  auto alloc = [&](size_t bytes)->void*{
    void* r = (void*)p; p += (bytes + 255) & ~(size_t)255; return r;
  };
  u16*   X    = (u16*)alloc((size_t)NN*256*2);     // 51.2 MB
  u16*   Y    = (u16*)alloc((size_t)NN*256*2);     // 51.2 MB
  float* z    = (float*)alloc((size_t)NN*200*4);   // 80 MB
  int*   csr  = (int*)alloc((size_t)NE*4);
  int*   rowp = (int*)alloc((size_t)(NN+1)*4);
  int*   fill = (int*)alloc((size_t)NN*4);
  int*   dego = (int*)alloc((size_t)NN*4);
  int*   degi = (int*)alloc((size_t)NN*4);
  float* ns   = (float*)alloc((size_t)NN*4);
  float* nd   = (float*)alloc((size_t)NN*4);
  int*   texcl= (int*)alloc((size_t)NCHUNK*256*4);
  int*   partial = (int*)alloc((size_t)NCHUNK*4);
  int*   coff    = (int*)alloc((size_t)NCHUNK*4);
  float* bns  = (float*)alloc(200*4);
  float* bnq  = (float*)alloc(200*4);
  float* w2a  = (float*)alloc(400*4);
  float* cc2  = (float*)alloc(2*4);
  u16*   wt0  = (u16*)alloc((size_t)128*128*2);
  u16*   wt1  = (u16*)alloc((size_t)256*128*2);
  u16*   wt2  = (u16*)alloc((size_t)256*256*2);
  u16*   wtm1 = (u16*)alloc((size_t)200*256*2);

  int nblk = (NN + 255)/256;
  k_init_deg<<<nblk, 256, 0, stream>>>(dego, degi);
  k_hist<<<2048, 256, 0, stream>>>(src, dst, dego, degi);
  k_norm<<<nblk, 256, 0, stream>>>(dego, degi, ns, nd);
  k_scan1<<<NCHUNK, 256, 0, stream>>>(degi, texcl, partial);
  k_scan2<<<1, 64, 0, stream>>>(partial, coff);
  k_scan3<<<NCHUNK, 256, 0, stream>>>(degi, texcl, coff, rowp, fill);
  k_fill<<<2048, 256, 0, stream>>>(src, dst, rowp, fill, csr);

  // weight transposes (tiny)
  k_transposew<<<dim3(8,8),   dim3(16,16), 0, stream>>>(W0,  wt0, 128, 128);
  k_transposew<<<dim3(16,8),  dim3(16,16), 0, stream>>>(W1,  wt1, 128, 256);
  k_transposew<<<dim3(16,16), dim3(16,16), 0, stream>>>(W2,  wt2, 256, 256);
  k_transposew<<<dim3(13,16), dim3(16,16), 0, stream>>>(Wm1, wtm1, 256, 200);

  // features * ns -> bf16
  k_cvt<<<(NN*32 + 255)/256, 256, 0, stream>>>(features, ns, X);

  int sblk = (NN + 3)/4;           // 1 wave per node
  int gblk = (NN + 127)/128;       // GEMM row blocks

  // layer 0
  k_spmm_b<128><<<sblk, 256, 0, stream>>>(X, rowp, degi, csr, nd, Y);
  k_gemm_mfma<0><<<dim3(1,gblk), 256, 0, stream>>>(Y, wt0, b0, ns, X, nullptr, NN, 128, 128);
  // layer 1
  k_spmm_b<128><<<sblk, 256, 0, stream>>>(X, rowp, degi, csr, nd, Y);
  k_gemm_mfma<0><<<dim3(2,gblk), 256, 0, stream>>>(Y, wt1, b1, ns, X, nullptr, NN, 128, 256);
  // layer 2
  k_spmm_b<256><<<sblk, 256, 0, stream>>>(X, rowp, degi, csr, nd, Y);
  k_gemm_mfma<1><<<dim3(2,gblk), 256, 0, stream>>>(Y, wt2, b2, nullptr, X, nullptr, NN, 256, 256);
  // MLP hidden: z = relu(h3 @ Wm1 + bm1)
  k_gemm_mfma<2><<<dim3(2,gblk), 256, 0, stream>>>(X, wtm1, bm1, nullptr, nullptr, z, NN, 256, 200);

  // batchnorm + final linear
  k_bn0<<<1, 256, 0, stream>>>(bns, bnq);
  k_bn1<<<1024, 256, 0, stream>>>(z, bns, bnq);
  k_bn2<<<1, 256, 0, stream>>>(bns, bnq, gamma, beta, Wm2, bm2, w2a, cc2);
  k_final<<<sblk, 256, 0, stream>>>(z, w2a, cc2, out);
}

// Round 3
// 1195.593 us; speedup vs baseline: 1.8642x; 1.4406x over previous
//
#include <hip/hip_runtime.h>

#define NN 100000
#define NE 3200000
#define NCHUNK 49   // ceil(NN / 2048)

typedef unsigned short u16;
typedef unsigned int u32;
typedef __attribute__((ext_vector_type(8))) short short8v;
typedef __attribute__((ext_vector_type(4))) float f32x4;

__device__ __forceinline__ u16 f2b(float f){
  u32 u = __float_as_uint(f);
  u32 r = (u + 0x7fffu + ((u >> 16) & 1u)) >> 16;
  return (u16)r;
}
__device__ __forceinline__ float b2f(u16 b){
  return __uint_as_float(((u32)b) << 16);
}

// ---------------- degrees / norms ----------------
__global__ void k_init_deg(int* __restrict__ dego, int* __restrict__ degi){
  int i = blockIdx.x*256 + threadIdx.x;
  if(i < NN){ dego[i]=1; degi[i]=1; }   // self-loop included
}

__global__ void k_hist(const int* __restrict__ src, const int* __restrict__ dst,
                       int* __restrict__ dego, int* __restrict__ degi){
  int stride = gridDim.x*blockDim.x;
  for(int e = blockIdx.x*blockDim.x + threadIdx.x; e < NE; e += stride){
    atomicAdd(&dego[src[e]], 1);
    atomicAdd(&degi[dst[e]], 1);
  }
}

__global__ void k_norm(const int* __restrict__ dego, const int* __restrict__ degi,
                       float* __restrict__ ns, float* __restrict__ nd){
  int i = blockIdx.x*256 + threadIdx.x;
  if(i < NN){ ns[i] = rsqrtf((float)dego[i]); nd[i] = rsqrtf((float)degi[i]); }
}

// ---------------- scan for CSR row_ptr ----------------
__global__ void k_scan1(const int* __restrict__ degi, int* __restrict__ texcl,
                        int* __restrict__ partial){
  __shared__ int s[256];
  int b = blockIdx.x, t = threadIdx.x;
  int base = b*2048 + t*8;
  int sum = 0;
  #pragma unroll
  for(int j=0;j<8;j++){ int v = base+j; if(v<NN) sum += degi[v]-1; }
  s[t] = sum; __syncthreads();
  for(int off=1; off<256; off<<=1){
    int v = (t>=off) ? s[t-off] : 0;
    __syncthreads();
    s[t] += v;
    __syncthreads();
  }
  texcl[b*256+t] = s[t] - sum;
  if(t==255) partial[b] = s[255];
}

__global__ void k_scan2(const int* __restrict__ partial, int* __restrict__ coff){
  if(threadIdx.x==0){
    int run=0;
    for(int i=0;i<NCHUNK;i++){ coff[i]=run; run+=partial[i]; }
  }
}

__global__ void k_scan3(const int* __restrict__ degi, const int* __restrict__ texcl,
                        const int* __restrict__ coff, int* __restrict__ rowp,
                        int* __restrict__ fill){
  int b = blockIdx.x, t = threadIdx.x;
  int base = b*2048 + t*8;
  int run = coff[b] + texcl[b*256+t];
  #pragma unroll
  for(int j=0;j<8;j++){
    int v = base+j;
    if(v<NN){ rowp[v]=run; fill[v]=0; run += degi[v]-1; }
  }
}

__global__ void k_fill(const int* __restrict__ src, const int* __restrict__ dst,
                       const int* __restrict__ rowp, int* __restrict__ fill,
                       int* __restrict__ csr){
  int stride = gridDim.x*blockDim.x;
  for(int e = blockIdx.x*blockDim.x + threadIdx.x; e < NE; e += stride){
    int v = dst[e];
    int pos = rowp[v] + atomicAdd(&fill[v], 1);
    csr[pos] = src[e];
  }
}

// ---------------- convert features*ns -> bf16 ----------------
__global__ void k_cvt(const float* __restrict__ f, const float* __restrict__ ns,
                      u16* __restrict__ out){
  int i = blockIdx.x*256 + threadIdx.x;    // groups of 4 elems, 32 groups/row
  if(i >= NN*32) return;
  int row = i >> 5;
  float nsv = ns[row];
  float4 v = *(const float4*)(f + (size_t)i*4);
  u32 w0 = (u32)f2b(v.x*nsv) | ((u32)f2b(v.y*nsv) << 16);
  u32 w1 = (u32)f2b(v.z*nsv) | ((u32)f2b(v.w*nsv) << 16);
  *(uint2*)(out + (size_t)i*4) = make_uint2(w0, w1);
}

// ---------------- transpose weight -> bf16 N x K ----------------
__global__ void k_transposew(const float* __restrict__ W, u16* __restrict__ Wt,
                             int K, int N){
  int n = blockIdx.x*16 + threadIdx.x;
  int k = blockIdx.y*16 + threadIdx.y;
  if(n < N && k < K) Wt[(size_t)n*K + k] = f2b(W[(size_t)k*N + n]);
}

// ---------------- SpMM: 1 wave/node, EP edge-groups in parallel ----------------
// h: bf16 rows premultiplied by norm_src. out: bf16 rows * norm_dst.
template<int DIM, int EP>
__global__ void k_spmm_b(const u16* __restrict__ h, const int* __restrict__ rowp,
                         const int* __restrict__ degi, const int* __restrict__ csr,
                         const float* __restrict__ nd, u16* __restrict__ out){
  constexpr int G  = 64/EP;          // lanes per edge-group
  constexpr int NV = DIM/(G*8);      // uint4 (8 bf16) loads per lane
  int w = (blockIdx.x*blockDim.x + threadIdx.x) >> 6;
  int lane = threadIdx.x & 63;
  int g  = lane / G;
  int gl = lane % G;
  if(w >= NN) return;
  const uint4* hv = (const uint4*)h;       // DIM/8 uint4 per row
  float acc[NV*8];
  #pragma unroll
  for(int i=0;i<NV*8;i++) acc[i]=0.f;

  auto addrow = [&](int node){
    #pragma unroll
    for(int v4=0; v4<NV; v4++){
      uint4 v = hv[(size_t)node*(DIM/8) + gl*NV + v4];
      u32 wd[4] = {v.x, v.y, v.z, v.w};
      #pragma unroll
      for(int i=0;i<4;i++){
        acc[v4*8 + 2*i]   += b2f((u16)(wd[i] & 0xffff));
        acc[v4*8 + 2*i+1] += b2f((u16)(wd[i] >> 16));
      }
    }
  };

  if(g == 0) addrow(w);            // self-loop term
  int start = rowp[w];
  int cnt = degi[w]-1;
  for(int j=g; j<cnt; j+=EP) addrow(csr[start+j]);

  // combine edge-groups
  #pragma unroll
  for(int i=0;i<NV*8;i++){
    if(EP >= 4) acc[i] += __shfl_xor(acc[i], 16);
    acc[i] += __shfl_xor(acc[i], 32);
  }
  if(g == 0){
    float ndv = nd[w];
    #pragma unroll
    for(int v4=0; v4<NV; v4++){
      u32 o[4];
      #pragma unroll
      for(int i=0;i<4;i++){
        o[i] = (u32)f2b(acc[v4*8+2*i]*ndv) | ((u32)f2b(acc[v4*8+2*i+1]*ndv) << 16);
      }
      *(uint4*)(out + (size_t)w*DIM + (gl*NV + v4)*8) = make_uint4(o[0],o[1],o[2],o[3]);
    }
  }
}

// ---------------- bf16 MFMA GEMM: out = relu(A @ Wt^T + bias) ----------------
// A: M x K bf16 row-major. Bt: N x K bf16 row-major (= W^T). fp32 accum.
// OUTMODE 0: bf16 out * ns[row]; 1: bf16 out; 2: fp32 out + BN col sums.
template<int OUTMODE>
__global__ __launch_bounds__(256) void k_gemm_mfma(
    const u16* __restrict__ A, const u16* __restrict__ Bt,
    const float* __restrict__ bias, const float* __restrict__ ns,
    u16* __restrict__ outb, float* __restrict__ outf,
    float* __restrict__ bns, float* __restrict__ bnq,
    int M, int K, int Nn)
{
  __shared__ u16 As[128*32];
  __shared__ u16 Bs[128*32];
  int t = threadIdx.x;
  int wave = t >> 6, lane = t & 63;
  int l15 = lane & 15, l4 = lane >> 4;
  int wr = (wave >> 1)*64, wc = (wave & 1)*64;
  int row0 = blockIdx.y*128, col0 = blockIdx.x*128;

  f32x4 acc[4][4];
  #pragma unroll
  for(int m=0;m<4;m++)
    #pragma unroll
    for(int n=0;n<4;n++) acc[m][n] = (f32x4)(0.f);

  int st_r = t >> 1;
  int kc0 = (t & 1)*2;
  int sw  = (st_r >> 1) & 3;
  int c0 = kc0 ^ sw, c1 = (kc0+1) ^ sw;
  bool avalid = (row0 + st_r) < M;
  bool bvalid = (col0 + st_r) < Nn;
  const u16* Ap = A  + (size_t)(row0 + st_r)*K + kc0*8;
  const u16* Bp = Bt + (size_t)(col0 + st_r)*K + kc0*8;

  for(int k0 = 0; k0 < K; k0 += 32){
    uint4 va0 = make_uint4(0,0,0,0), va1 = va0, vb0 = va0, vb1 = va0;
    if(avalid){ va0 = *(const uint4*)(Ap + k0); va1 = *(const uint4*)(Ap + k0 + 8); }
    if(bvalid){ vb0 = *(const uint4*)(Bp + k0); vb1 = *(const uint4*)(Bp + k0 + 8); }
    __syncthreads();
    *(uint4*)&As[st_r*32 + c0*8] = va0;
    *(uint4*)&As[st_r*32 + c1*8] = va1;
    *(uint4*)&Bs[st_r*32 + c0*8] = vb0;
    *(uint4*)&Bs[st_r*32 + c1*8] = vb1;
    __syncthreads();

    short8v af[4], bg[4];
    #pragma unroll
    for(int m=0;m<4;m++){
      int r = wr + m*16 + l15;
      int kc = l4 ^ ((r >> 1) & 3);
      af[m] = *(const short8v*)&As[r*32 + kc*8];
    }
    #pragma unroll
    for(int n=0;n<4;n++){
      int r = wc + n*16 + l15;
      int kc = l4 ^ ((r >> 1) & 3);
      bg[n] = *(const short8v*)&Bs[r*32 + kc*8];
    }
    #pragma unroll
    for(int m=0;m<4;m++)
      #pragma unroll
      for(int n=0;n<4;n++)
        acc[m][n] = __builtin_amdgcn_mfma_f32_16x16x32_bf16(af[m], bg[n], acc[m][n], 0, 0, 0);
    __syncthreads();
  }

  float nsv[4][4];
  if(OUTMODE == 0){
    #pragma unroll
    for(int m=0;m<4;m++)
      #pragma unroll
      for(int r=0;r<4;r++){
        int gr = row0 + wr + m*16 + l4*4 + r;
        nsv[m][r] = (gr < M) ? ns[gr] : 0.f;
      }
  }
  #pragma unroll
  for(int n=0;n<4;n++){
    int gc = col0 + wc + n*16 + l15;
    float bv = (gc < Nn) ? bias[gc] : 0.f;
    float s = 0.f, q = 0.f;
    #pragma unroll
    for(int m=0;m<4;m++){
      #pragma unroll
      for(int r=0;r<4;r++){
        int gr = row0 + wr + m*16 + l4*4 + r;
        bool ok = (gr < M) && (gc < Nn);
        float v = ok ? fmaxf(acc[m][n][r] + bv, 0.f) : 0.f;
        if(ok){
          if(OUTMODE == 0)      outb[(size_t)gr*Nn + gc] = f2b(v * nsv[m][r]);
          else if(OUTMODE == 1) outb[(size_t)gr*Nn + gc] = f2b(v);
          else                  outf[(size_t)gr*Nn + gc] = v;
        }
        if(OUTMODE == 2){ s += v; q += v*v; }
      }
    }
    if(OUTMODE == 2){
      s += __shfl_xor(s, 16); s += __shfl_xor(s, 32);
      q += __shfl_xor(q, 16); q += __shfl_xor(q, 32);
      if(l4 == 0 && gc < Nn){ atomicAdd(&bns[gc], s); atomicAdd(&bnq[gc], q); }
    }
  }
}

// ---------------- batchnorm finalize + fused final linear ----------------
__global__ void k_bn0(float* __restrict__ s, float* __restrict__ q){
  int t = threadIdx.x;
  if(t<200){ s[t]=0.f; q[t]=0.f; }
}

__global__ void k_bn2(const float* __restrict__ bns, const float* __restrict__ bnq,
                      const float* __restrict__ gamma, const float* __restrict__ beta,
                      const float* __restrict__ Wm2, const float* __restrict__ bm2,
                      float* __restrict__ w2a, float* __restrict__ cc2){
  __shared__ float c0s[200];
  int t = threadIdx.x;
  if(t<200){
    float mu  = bns[t] * (1.0f/NN);
    float var = bnq[t] * (1.0f/NN) - mu*mu;
    float a   = rsqrtf(var + 1e-5f) * gamma[t];
    w2a[t*2+0] = a*Wm2[t*2+0];
    w2a[t*2+1] = a*Wm2[t*2+1];
    c0s[t] = beta[t] - mu*a;
  }
  __syncthreads();
  if(t<2){
    float cst = bm2[t];
    for(int k=0;k<200;k++) cst += c0s[k]*Wm2[k*2+t];
    cc2[t] = cst;
  }
}

__global__ void k_final(const float* __restrict__ z, const float* __restrict__ w2a,
                        const float* __restrict__ cc2, float* __restrict__ out){
  int lane = threadIdx.x & 63;
  int gw = (blockIdx.x*blockDim.x + threadIdx.x) >> 6;
  if(gw >= NN) return;
  const float* zr = z + (size_t)gw*200;
  float p0=0.f, p1=0.f;
  #pragma unroll
  for(int i=0;i<4;i++){
    int c = lane + i*64;
    if(c<200){ float x=zr[c]; p0 += x*w2a[c*2+0]; p1 += x*w2a[c*2+1]; }
  }
  for(int off=32; off>0; off>>=1){
    p0 += __shfl_down(p0, off);
    p1 += __shfl_down(p1, off);
  }
  if(lane==0){ out[gw*2+0] = p0 + cc2[0]; out[gw*2+1] = p1 + cc2[1]; }
}

// ---------------- launch ----------------
extern "C" void kernel_launch(void* const* d_in, const int* in_sizes, int n_in,
                              void* d_out, int out_size, void* d_ws, size_t ws_size,
                              hipStream_t stream) {
  const float* features = (const float*)d_in[0];
  const int*   src = (const int*)d_in[1];
  const int*   dst = (const int*)d_in[2];
  const float* W0  = (const float*)d_in[3];
  const float* b0  = (const float*)d_in[4];
  const float* W1  = (const float*)d_in[5];
  const float* b1  = (const float*)d_in[6];
  const float* W2  = (const float*)d_in[7];
  const float* b2  = (const float*)d_in[8];
  const float* Wm1 = (const float*)d_in[9];
  const float* bm1 = (const float*)d_in[10];
  const float* gamma = (const float*)d_in[11];
  const float* beta  = (const float*)d_in[12];
  const float* Wm2 = (const float*)d_in[13];
  const float* bm2 = (const float*)d_in[14];
  float* out = (float*)d_out;

  char* p = (char*)d_ws;
  auto alloc = [&](size_t bytes)->void*{
    void* r = (void*)p; p += (bytes + 255) & ~(size_t)255; return r;
  };
  u16*   X    = (u16*)alloc((size_t)NN*256*2);
  u16*   Y    = (u16*)alloc((size_t)NN*256*2);
  float* z    = (float*)alloc((size_t)NN*200*4);
  int*   csr  = (int*)alloc((size_t)NE*4);
  int*   rowp = (int*)alloc((size_t)(NN+1)*4);
  int*   fill = (int*)alloc((size_t)NN*4);
  int*   dego = (int*)alloc((size_t)NN*4);
  int*   degi = (int*)alloc((size_t)NN*4);
  float* ns   = (float*)alloc((size_t)NN*4);
  float* nd   = (float*)alloc((size_t)NN*4);
  int*   texcl= (int*)alloc((size_t)NCHUNK*256*4);
  int*   partial = (int*)alloc((size_t)NCHUNK*4);
  int*   coff    = (int*)alloc((size_t)NCHUNK*4);
  float* bns  = (float*)alloc(200*4);
  float* bnq  = (float*)alloc(200*4);
  float* w2a  = (float*)alloc(400*4);
  float* cc2  = (float*)alloc(2*4);
  u16*   wt0  = (u16*)alloc((size_t)128*128*2);
  u16*   wt1  = (u16*)alloc((size_t)256*128*2);
  u16*   wt2  = (u16*)alloc((size_t)256*256*2);
  u16*   wtm1 = (u16*)alloc((size_t)200*256*2);

  int nblk = (NN + 255)/256;
  k_init_deg<<<nblk, 256, 0, stream>>>(dego, degi);
  k_hist<<<2048, 256, 0, stream>>>(src, dst, dego, degi);
  k_norm<<<nblk, 256, 0, stream>>>(dego, degi, ns, nd);
  k_scan1<<<NCHUNK, 256, 0, stream>>>(degi, texcl, partial);
  k_scan2<<<1, 64, 0, stream>>>(partial, coff);
  k_scan3<<<NCHUNK, 256, 0, stream>>>(degi, texcl, coff, rowp, fill);
  k_fill<<<2048, 256, 0, stream>>>(src, dst, rowp, fill, csr);
  k_bn0<<<1, 256, 0, stream>>>(bns, bnq);

  // weight transposes (tiny)
  k_transposew<<<dim3(8,8),   dim3(16,16), 0, stream>>>(W0,  wt0, 128, 128);
  k_transposew<<<dim3(16,8),  dim3(16,16), 0, stream>>>(W1,  wt1, 128, 256);
  k_transposew<<<dim3(16,16), dim3(16,16), 0, stream>>>(W2,  wt2, 256, 256);
  k_transposew<<<dim3(13,16), dim3(16,16), 0, stream>>>(Wm1, wtm1, 256, 200);

  // features * ns -> bf16
  k_cvt<<<(NN*32 + 255)/256, 256, 0, stream>>>(features, ns, X);

  int sblk = (NN + 3)/4;           // 1 wave per node
  int gblk = (NN + 127)/128;       // GEMM row blocks

  // layer 0
  k_spmm_b<128,4><<<sblk, 256, 0, stream>>>(X, rowp, degi, csr, nd, Y);
  k_gemm_mfma<0><<<dim3(1,gblk), 256, 0, stream>>>(Y, wt0, b0, ns, X, nullptr, nullptr, nullptr, NN, 128, 128);
  // layer 1
  k_spmm_b<128,4><<<sblk, 256, 0, stream>>>(X, rowp, degi, csr, nd, Y);
  k_gemm_mfma<0><<<dim3(2,gblk), 256, 0, stream>>>(Y, wt1, b1, ns, X, nullptr, nullptr, nullptr, NN, 128, 256);
  // layer 2
  k_spmm_b<256,4><<<sblk, 256, 0, stream>>>(X, rowp, degi, csr, nd, Y);
  k_gemm_mfma<1><<<dim3(2,gblk), 256, 0, stream>>>(Y, wt2, b2, nullptr, X, nullptr, nullptr, nullptr, NN, 256, 256);
  // MLP hidden: z = relu(h3 @ Wm1 + bm1) + fused BN column stats
  k_gemm_mfma<2><<<dim3(2,gblk), 256, 0, stream>>>(X, wtm1, bm1, nullptr, nullptr, z, bns, bnq, NN, 256, 200);

  // batchnorm finalize + final linear
  k_bn2<<<1, 256, 0, stream>>>(bns, bnq, gamma, beta, Wm2, bm2, w2a, cc2);
  k_final<<<sblk, 256, 0, stream>>>(z, w2a, cc2, out);
}

// Round 4
// 1113.587 us; speedup vs baseline: 2.0015x; 1.0736x over previous
//
#include <hip/hip_runtime.h>

#define NN 100000
#define NE 3200000
#define NREP 8
#define NHB 2048                 // blocks for hist/fill
#define CHK ((NE + NHB - 1)/NHB) // edges per block = 1563
#define NP (NN*NREP)             // 800000 scan elements
#define NCHUNK2 ((NP + 2047)/2048) // 391

typedef unsigned short u16;
typedef unsigned int u32;
typedef __attribute__((ext_vector_type(8))) short short8v;
typedef __attribute__((ext_vector_type(4))) float f32x4;

__device__ __forceinline__ u16 f2b(float f){
  u32 u = __float_as_uint(f);
  u32 r = (u + 0x7fffu + ((u >> 16) & 1u)) >> 16;
  return (u16)r;
}
__device__ __forceinline__ float b2f(u16 b){
  return __uint_as_float(((u32)b) << 16);
}

// ---------------- zero replicated counters ----------------
__global__ void k_zero(int* __restrict__ buf, int n){
  int i = blockIdx.x*256 + threadIdx.x;
  if(i < n) buf[i] = 0;
}

// ---------------- replicated degree histogram ----------------
// dego8[r*NN+v] counts src occurrences in edge-class r; cnt8 same for dst.
__global__ void k_hist8(const int* __restrict__ src, const int* __restrict__ dst,
                        int* __restrict__ dego8, int* __restrict__ cnt8){
  int b = blockIdx.x;
  int r = b & (NREP-1);
  int start = b*CHK, end = min(start + CHK, NE);
  for(int e = start + threadIdx.x; e < end; e += 256){
    atomicAdd(&dego8[r*NN + src[e]], 1);
    atomicAdd(&cnt8[r*NN + dst[e]], 1);
  }
}

// ---------------- merge replicas -> norms + degi ----------------
__global__ void k_norm8(const int* __restrict__ dego8, const int* __restrict__ cnt8,
                        float* __restrict__ ns, float* __restrict__ nd,
                        int* __restrict__ degi){
  int i = blockIdx.x*256 + threadIdx.x;
  if(i >= NN) return;
  int so = 1, si = 1;
  #pragma unroll
  for(int r=0;r<NREP;r++){ so += dego8[r*NN+i]; si += cnt8[r*NN+i]; }
  ns[i] = rsqrtf((float)so);
  nd[i] = rsqrtf((float)si);
  degi[i] = si;
}

// ---------------- two-level exclusive scan over 800K (v-major, value cnt8[r][v]) ----
__global__ void k2_scan1(const int* __restrict__ cnt8, int* __restrict__ texcl,
                         int* __restrict__ partial){
  __shared__ int s[256];
  int b = blockIdx.x, t = threadIdx.x;
  int base = b*2048 + t*8;
  int sum = 0;
  #pragma unroll
  for(int j=0;j<8;j++){
    int p = base+j;
    if(p < NP) sum += cnt8[(p & (NREP-1))*NN + (p >> 3)];
  }
  s[t] = sum; __syncthreads();
  for(int off=1; off<256; off<<=1){
    int v = (t>=off) ? s[t-off] : 0;
    __syncthreads();
    s[t] += v;
    __syncthreads();
  }
  texcl[b*256+t] = s[t] - sum;
  if(t==255) partial[b] = s[255];
}

__global__ void k2_scan2(const int* __restrict__ partial, int* __restrict__ coff){
  if(threadIdx.x==0){
    int run=0;
    for(int i=0;i<NCHUNK2;i++){ coff[i]=run; run+=partial[i]; }
  }
}

__global__ void k2_scan3(const int* __restrict__ cnt8, const int* __restrict__ texcl,
                         const int* __restrict__ coff, int* __restrict__ ex8,
                         int* __restrict__ rowp){
  int b = blockIdx.x, t = threadIdx.x;
  int base = b*2048 + t*8;
  int run = coff[b] + texcl[b*256+t];
  #pragma unroll
  for(int j=0;j<8;j++){
    int p = base+j;
    if(p < NP){
      ex8[p] = run;
      if((p & (NREP-1)) == 0) rowp[p >> 3] = run;
      run += cnt8[(p & (NREP-1))*NN + (p >> 3)];
    }
  }
}

// ---------------- CSR fill, replica-spread atomics ----------------
__global__ void k_fill8(const int* __restrict__ src, const int* __restrict__ dst,
                        const int* __restrict__ ex8, int* __restrict__ fill8,
                        int* __restrict__ csr){
  int b = blockIdx.x;
  int r = b & (NREP-1);
  int start = b*CHK, end = min(start + CHK, NE);
  for(int e = start + threadIdx.x; e < end; e += 256){
    int v = dst[e];
    int pos = ex8[v*NREP + r] + atomicAdd(&fill8[r*NN + v], 1);
    csr[pos] = src[e];
  }
}

// ---------------- convert features*ns -> bf16 ----------------
__global__ void k_cvt(const float* __restrict__ f, const float* __restrict__ ns,
                      u16* __restrict__ out){
  int i = blockIdx.x*256 + threadIdx.x;    // groups of 4 elems, 32 groups/row
  if(i >= NN*32) return;
  int row = i >> 5;
  float nsv = ns[row];
  float4 v = *(const float4*)(f + (size_t)i*4);
  u32 w0 = (u32)f2b(v.x*nsv) | ((u32)f2b(v.y*nsv) << 16);
  u32 w1 = (u32)f2b(v.z*nsv) | ((u32)f2b(v.w*nsv) << 16);
  *(uint2*)(out + (size_t)i*4) = make_uint2(w0, w1);
}

// ---------------- transpose weight -> bf16 N x K ----------------
__global__ void k_transposew(const float* __restrict__ W, u16* __restrict__ Wt,
                             int K, int N){
  int n = blockIdx.x*16 + threadIdx.x;
  int k = blockIdx.y*16 + threadIdx.y;
  if(n < N && k < K) Wt[(size_t)n*K + k] = f2b(W[(size_t)k*N + n]);
}

// ---------------- SpMM: 1 wave/node, EP edge-groups in parallel ----------------
template<int DIM, int EP>
__global__ void k_spmm_b(const u16* __restrict__ h, const int* __restrict__ rowp,
                         const int* __restrict__ degi, const int* __restrict__ csr,
                         const float* __restrict__ nd, u16* __restrict__ out){
  constexpr int G  = 64/EP;          // lanes per edge-group
  constexpr int NV = DIM/(G*8);      // uint4 (8 bf16) loads per lane
  int w = (blockIdx.x*blockDim.x + threadIdx.x) >> 6;
  int lane = threadIdx.x & 63;
  int g  = lane / G;
  int gl = lane % G;
  if(w >= NN) return;
  const uint4* hv = (const uint4*)h;       // DIM/8 uint4 per row
  float acc[NV*8];
  #pragma unroll
  for(int i=0;i<NV*8;i++) acc[i]=0.f;

  auto addrow = [&](int node){
    #pragma unroll
    for(int v4=0; v4<NV; v4++){
      uint4 v = hv[(size_t)node*(DIM/8) + gl*NV + v4];
      u32 wd[4] = {v.x, v.y, v.z, v.w};
      #pragma unroll
      for(int i=0;i<4;i++){
        acc[v4*8 + 2*i]   += b2f((u16)(wd[i] & 0xffff));
        acc[v4*8 + 2*i+1] += b2f((u16)(wd[i] >> 16));
      }
    }
  };

  if(g == 0) addrow(w);            // self-loop term
  int start = rowp[w];
  int cnt = degi[w]-1;
  for(int j=g; j<cnt; j+=EP) addrow(csr[start+j]);

  // combine edge-groups
  #pragma unroll
  for(int i=0;i<NV*8;i++){
    if(EP >= 8) acc[i] += __shfl_xor(acc[i], 8);
    if(EP >= 4) acc[i] += __shfl_xor(acc[i], 16);
    acc[i] += __shfl_xor(acc[i], 32);
  }
  if(g == 0){
    float ndv = nd[w];
    #pragma unroll
    for(int v4=0; v4<NV; v4++){
      u32 o[4];
      #pragma unroll
      for(int i=0;i<4;i++){
        o[i] = (u32)f2b(acc[v4*8+2*i]*ndv) | ((u32)f2b(acc[v4*8+2*i+1]*ndv) << 16);
      }
      *(uint4*)(out + (size_t)w*DIM + (gl*NV + v4)*8) = make_uint4(o[0],o[1],o[2],o[3]);
    }
  }
}

// ---------------- bf16 MFMA GEMM: out = relu(A @ Wt^T + bias) ----------------
// OUTMODE 0: bf16 out * ns[row]; 1: bf16 out; 2: fp32 out + BN col sums.
template<int OUTMODE>
__global__ __launch_bounds__(256) void k_gemm_mfma(
    const u16* __restrict__ A, const u16* __restrict__ Bt,
    const float* __restrict__ bias, const float* __restrict__ ns,
    u16* __restrict__ outb, float* __restrict__ outf,
    float* __restrict__ bns, float* __restrict__ bnq,
    int M, int K, int Nn)
{
  __shared__ u16 As[128*32];
  __shared__ u16 Bs[128*32];
  int t = threadIdx.x;
  int wave = t >> 6, lane = t & 63;
  int l15 = lane & 15, l4 = lane >> 4;
  int wr = (wave >> 1)*64, wc = (wave & 1)*64;
  int row0 = blockIdx.y*128, col0 = blockIdx.x*128;

  f32x4 acc[4][4];
  #pragma unroll
  for(int m=0;m<4;m++)
    #pragma unroll
    for(int n=0;n<4;n++) acc[m][n] = (f32x4)(0.f);

  int st_r = t >> 1;
  int kc0 = (t & 1)*2;
  int sw  = (st_r >> 1) & 3;
  int c0 = kc0 ^ sw, c1 = (kc0+1) ^ sw;
  bool avalid = (row0 + st_r) < M;
  bool bvalid = (col0 + st_r) < Nn;
  const u16* Ap = A  + (size_t)(row0 + st_r)*K + kc0*8;
  const u16* Bp = Bt + (size_t)(col0 + st_r)*K + kc0*8;

  for(int k0 = 0; k0 < K; k0 += 32){
    uint4 va0 = make_uint4(0,0,0,0), va1 = va0, vb0 = va0, vb1 = va0;
    if(avalid){ va0 = *(const uint4*)(Ap + k0); va1 = *(const uint4*)(Ap + k0 + 8); }
    if(bvalid){ vb0 = *(const uint4*)(Bp + k0); vb1 = *(const uint4*)(Bp + k0 + 8); }
    __syncthreads();
    *(uint4*)&As[st_r*32 + c0*8] = va0;
    *(uint4*)&As[st_r*32 + c1*8] = va1;
    *(uint4*)&Bs[st_r*32 + c0*8] = vb0;
    *(uint4*)&Bs[st_r*32 + c1*8] = vb1;
    __syncthreads();

    short8v af[4], bg[4];
    #pragma unroll
    for(int m=0;m<4;m++){
      int r = wr + m*16 + l15;
      int kc = l4 ^ ((r >> 1) & 3);
      af[m] = *(const short8v*)&As[r*32 + kc*8];
    }
    #pragma unroll
    for(int n=0;n<4;n++){
      int r = wc + n*16 + l15;
      int kc = l4 ^ ((r >> 1) & 3);
      bg[n] = *(const short8v*)&Bs[r*32 + kc*8];
    }
    #pragma unroll
    for(int m=0;m<4;m++)
      #pragma unroll
      for(int n=0;n<4;n++)
        acc[m][n] = __builtin_amdgcn_mfma_f32_16x16x32_bf16(af[m], bg[n], acc[m][n], 0, 0, 0);
    __syncthreads();
  }

  float nsv[4][4];
  if(OUTMODE == 0){
    #pragma unroll
    for(int m=0;m<4;m++)
      #pragma unroll
      for(int r=0;r<4;r++){
        int gr = row0 + wr + m*16 + l4*4 + r;
        nsv[m][r] = (gr < M) ? ns[gr] : 0.f;
      }
  }
  #pragma unroll
  for(int n=0;n<4;n++){
    int gc = col0 + wc + n*16 + l15;
    float bv = (gc < Nn) ? bias[gc] : 0.f;
    float s = 0.f, q = 0.f;
    #pragma unroll
    for(int m=0;m<4;m++){
      #pragma unroll
      for(int r=0;r<4;r++){
        int gr = row0 + wr + m*16 + l4*4 + r;
        bool ok = (gr < M) && (gc < Nn);
        float v = ok ? fmaxf(acc[m][n][r] + bv, 0.f) : 0.f;
        if(ok){
          if(OUTMODE == 0)      outb[(size_t)gr*Nn + gc] = f2b(v * nsv[m][r]);
          else if(OUTMODE == 1) outb[(size_t)gr*Nn + gc] = f2b(v);
          else                  outf[(size_t)gr*Nn + gc] = v;
        }
        if(OUTMODE == 2){ s += v; q += v*v; }
      }
    }
    if(OUTMODE == 2){
      s += __shfl_xor(s, 16); s += __shfl_xor(s, 32);
      q += __shfl_xor(q, 16); q += __shfl_xor(q, 32);
      if(l4 == 0 && gc < Nn){ atomicAdd(&bns[gc], s); atomicAdd(&bnq[gc], q); }
    }
  }
}

// ---------------- batchnorm finalize + fused final linear ----------------
__global__ void k_bn0(float* __restrict__ s, float* __restrict__ q){
  int t = threadIdx.x;
  if(t<200){ s[t]=0.f; q[t]=0.f; }
}

__global__ void k_bn2(const float* __restrict__ bns, const float* __restrict__ bnq,
                      const float* __restrict__ gamma, const float* __restrict__ beta,
                      const float* __restrict__ Wm2, const float* __restrict__ bm2,
                      float* __restrict__ w2a, float* __restrict__ cc2){
  __shared__ float c0s[200];
  int t = threadIdx.x;
  if(t<200){
    float mu  = bns[t] * (1.0f/NN);
    float var = bnq[t] * (1.0f/NN) - mu*mu;
    float a   = rsqrtf(var + 1e-5f) * gamma[t];
    w2a[t*2+0] = a*Wm2[t*2+0];
    w2a[t*2+1] = a*Wm2[t*2+1];
    c0s[t] = beta[t] - mu*a;
  }
  __syncthreads();
  if(t<2){
    float cst = bm2[t];
    for(int k=0;k<200;k++) cst += c0s[k]*Wm2[k*2+t];
    cc2[t] = cst;
  }
}

__global__ void k_final(const float* __restrict__ z, const float* __restrict__ w2a,
                        const float* __restrict__ cc2, float* __restrict__ out){
  int lane = threadIdx.x & 63;
  int gw = (blockIdx.x*blockDim.x + threadIdx.x) >> 6;
  if(gw >= NN) return;
  const float* zr = z + (size_t)gw*200;
  float p0=0.f, p1=0.f;
  #pragma unroll
  for(int i=0;i<4;i++){
    int c = lane + i*64;
    if(c<200){ float x=zr[c]; p0 += x*w2a[c*2+0]; p1 += x*w2a[c*2+1]; }
  }
  for(int off=32; off>0; off>>=1){
    p0 += __shfl_down(p0, off);
    p1 += __shfl_down(p1, off);
  }
  if(lane==0){ out[gw*2+0] = p0 + cc2[0]; out[gw*2+1] = p1 + cc2[1]; }
}

// ---------------- launch ----------------
extern "C" void kernel_launch(void* const* d_in, const int* in_sizes, int n_in,
                              void* d_out, int out_size, void* d_ws, size_t ws_size,
                              hipStream_t stream) {
  const float* features = (const float*)d_in[0];
  const int*   src = (const int*)d_in[1];
  const int*   dst = (const int*)d_in[2];
  const float* W0  = (const float*)d_in[3];
  const float* b0  = (const float*)d_in[4];
  const float* W1  = (const float*)d_in[5];
  const float* b1  = (const float*)d_in[6];
  const float* W2  = (const float*)d_in[7];
  const float* b2  = (const float*)d_in[8];
  const float* Wm1 = (const float*)d_in[9];
  const float* bm1 = (const float*)d_in[10];
  const float* gamma = (const float*)d_in[11];
  const float* beta  = (const float*)d_in[12];
  const float* Wm2 = (const float*)d_in[13];
  const float* bm2 = (const float*)d_in[14];
  float* out = (float*)d_out;

  char* p = (char*)d_ws;
  auto alloc = [&](size_t bytes)->void*{
    void* r = (void*)p; p += (bytes + 255) & ~(size_t)255; return r;
  };
  u16*   X    = (u16*)alloc((size_t)NN*256*2);
  u16*   Y    = (u16*)alloc((size_t)NN*256*2);
  float* z    = (float*)alloc((size_t)NN*200*4);
  int*   csr  = (int*)alloc((size_t)NE*4);
  int*   rep  = (int*)alloc((size_t)3*NP*4);     // dego8 | cnt8 | fill8
  int*   dego8 = rep;
  int*   cnt8  = rep + NP;
  int*   fill8 = rep + 2*NP;
  int*   ex8  = (int*)alloc((size_t)NP*4);
  int*   rowp = (int*)alloc((size_t)NN*4);
  int*   degi = (int*)alloc((size_t)NN*4);
  float* ns   = (float*)alloc((size_t)NN*4);
  float* nd   = (float*)alloc((size_t)NN*4);
  int*   texcl= (int*)alloc((size_t)NCHUNK2*256*4);
  int*   partial = (int*)alloc((size_t)NCHUNK2*4);
  int*   coff    = (int*)alloc((size_t)NCHUNK2*4);
  float* bns  = (float*)alloc(200*4);
  float* bnq  = (float*)alloc(200*4);
  float* w2a  = (float*)alloc(400*4);
  float* cc2  = (float*)alloc(2*4);
  u16*   wt0  = (u16*)alloc((size_t)128*128*2);
  u16*   wt1  = (u16*)alloc((size_t)256*128*2);
  u16*   wt2  = (u16*)alloc((size_t)256*256*2);
  u16*   wtm1 = (u16*)alloc((size_t)200*256*2);

  // graph prep
  k_zero<<<(3*NP + 255)/256, 256, 0, stream>>>(rep, 3*NP);
  k_hist8<<<NHB, 256, 0, stream>>>(src, dst, dego8, cnt8);
  k_norm8<<<(NN+255)/256, 256, 0, stream>>>(dego8, cnt8, ns, nd, degi);
  k2_scan1<<<NCHUNK2, 256, 0, stream>>>(cnt8, texcl, partial);
  k2_scan2<<<1, 64, 0, stream>>>(partial, coff);
  k2_scan3<<<NCHUNK2, 256, 0, stream>>>(cnt8, texcl, coff, ex8, rowp);
  k_fill8<<<NHB, 256, 0, stream>>>(src, dst, ex8, fill8, csr);
  k_bn0<<<1, 256, 0, stream>>>(bns, bnq);

  // weight transposes (tiny)
  k_transposew<<<dim3(8,8),   dim3(16,16), 0, stream>>>(W0,  wt0, 128, 128);
  k_transposew<<<dim3(16,8),  dim3(16,16), 0, stream>>>(W1,  wt1, 128, 256);
  k_transposew<<<dim3(16,16), dim3(16,16), 0, stream>>>(W2,  wt2, 256, 256);
  k_transposew<<<dim3(13,16), dim3(16,16), 0, stream>>>(Wm1, wtm1, 256, 200);

  // features * ns -> bf16
  k_cvt<<<(NN*32 + 255)/256, 256, 0, stream>>>(features, ns, X);

  int sblk = (NN + 3)/4;           // 1 wave per node
  int gblk = (NN + 127)/128;       // GEMM row blocks

  // layer 0
  k_spmm_b<128,8><<<sblk, 256, 0, stream>>>(X, rowp, degi, csr, nd, Y);
  k_gemm_mfma<0><<<dim3(1,gblk), 256, 0, stream>>>(Y, wt0, b0, ns, X, nullptr, nullptr, nullptr, NN, 128, 128);
  // layer 1
  k_spmm_b<128,8><<<sblk, 256, 0, stream>>>(X, rowp, degi, csr, nd, Y);
  k_gemm_mfma<0><<<dim3(2,gblk), 256, 0, stream>>>(Y, wt1, b1, ns, X, nullptr, nullptr, nullptr, NN, 128, 256);
  // layer 2
  k_spmm_b<256,8><<<sblk, 256, 0, stream>>>(X, rowp, degi, csr, nd, Y);
  k_gemm_mfma<1><<<dim3(2,gblk), 256, 0, stream>>>(Y, wt2, b2, nullptr, X, nullptr, nullptr, nullptr, NN, 256, 256);
  // MLP hidden: z = relu(h3 @ Wm1 + bm1) + fused BN column stats
  k_gemm_mfma<2><<<dim3(2,gblk), 256, 0, stream>>>(X, wtm1, bm1, nullptr, nullptr, z, bns, bnq, NN, 256, 200);

  // batchnorm finalize + final linear
  k_bn2<<<1, 256, 0, stream>>>(bns, bnq, gamma, beta, Wm2, bm2, w2a, cc2);
  k_final<<<sblk, 256, 0, stream>>>(z, w2a, cc2, out);
}

// Round 5
// 819.440 us; speedup vs baseline: 2.7200x; 1.3590x over previous
//
#include <hip/hip_runtime.h>

#define NN 100000
#define NE 3200000
#define NBUK 196                  // ceil(NN/512) buckets of 512 nodes
#define CAP 18432                 // max edges per bucket (E/NBUK=16327 + slack)
#define NAB 512                   // binning blocks
#define ECHK ((NE + NAB - 1)/NAB) // 6250 edges per binning block

typedef unsigned short u16;
typedef unsigned int u32;
typedef __attribute__((ext_vector_type(8))) short short8v;
typedef __attribute__((ext_vector_type(4))) float f32x4;

__device__ __forceinline__ u16 f2b(float f){
  u32 u = __float_as_uint(f);
  u32 r = (u + 0x7fffu + ((u >> 16) & 1u)) >> 16;
  return (u16)r;
}
__device__ __forceinline__ float b2f(u16 b){
  return __uint_as_float(((u32)b) << 16);
}

// ---------------- misc: weight transposes (fp32->bf16 NxK) + zero counters -------
__global__ void k_misc(const float* __restrict__ W0, const float* __restrict__ W1,
                       const float* __restrict__ W2, const float* __restrict__ Wm1,
                       u16* __restrict__ wt0, u16* __restrict__ wt1,
                       u16* __restrict__ wt2, u16* __restrict__ wtm1,
                       u32* __restrict__ gcntD, u32* __restrict__ gcntS,
                       float* __restrict__ bns, float* __restrict__ bnq){
  int i = blockIdx.x*256 + threadIdx.x;
  // segments: wt0 16384 | wt1 32768 | wt2 65536 | wtm1 51200 | gcnt 512 | bn 400
  if(i < 16384){
    int n = i >> 7, k = i & 127;                  // K=128,N=128
    wt0[i] = f2b(W0[k*128 + n]);
  } else if((i -= 16384) < 32768){
    int n = i >> 7, k = i & 127;                  // K=128,N=256
    wt1[i] = f2b(W1[k*256 + n]);
  } else if((i -= 32768) < 65536){
    int n = i >> 8, k = i & 255;                  // K=256,N=256
    wt2[i] = f2b(W2[k*256 + n]);
  } else if((i -= 65536) < 51200){
    int n = i >> 8, k = i & 255;                  // K=256,N=200
    wtm1[i] = f2b(Wm1[k*200 + n]);
  } else if((i -= 51200) < 512){
    if(i < 256) gcntD[i] = 0; else gcntS[i-256] = 0;
  } else if((i -= 512) < 400){
    if(i < 200) bns[i] = 0.f; else bnq[i-200] = 0.f;
  }
}

// ---------------- binning: scatter edges into node-range buckets ----------------
// pairD[b*CAP + j] = (src<<9) | (dst&511)  for dst-bucket b
// keyS [b*CAP + j] = src&511               for src-bucket b
__global__ __launch_bounds__(256) void k_bin(const int* __restrict__ src,
                      const int* __restrict__ dst,
                      u32* __restrict__ gcntD, u32* __restrict__ gcntS,
                      u32* __restrict__ pairD, u16* __restrict__ keyS){
  __shared__ u32 cntD[NBUK], cntS[NBUK], offD[NBUK], offS[NBUK];
  int t = threadIdx.x, b = blockIdx.x;
  for(int j=t; j<NBUK; j+=256){ cntD[j]=0; cntS[j]=0; }
  __syncthreads();
  int start = b*ECHK, end = min(start + ECHK, NE);
  for(int e = start + t; e < end; e += 256){
    atomicAdd(&cntD[dst[e] >> 9], 1u);
    atomicAdd(&cntS[src[e] >> 9], 1u);
  }
  __syncthreads();
  for(int j=t; j<NBUK; j+=256){
    offD[j] = atomicAdd(&gcntD[j], cntD[j]);
    offS[j] = atomicAdd(&gcntS[j], cntS[j]);
    cntD[j] = 0; cntS[j] = 0;     // reuse as fill
  }
  __syncthreads();
  for(int e = start + t; e < end; e += 256){
    int d = dst[e], s = src[e];
    int bd = d >> 9, bs = s >> 9;
    u32 pd = offD[bd] + atomicAdd(&cntD[bd], 1u);
    u32 ps = offS[bs] + atomicAdd(&cntS[bs], 1u);
    if(pd < CAP) pairD[bd*CAP + pd] = ((u32)s << 9) | (u32)(d & 511);
    if(ps < CAP) keyS[bs*CAP + ps] = (u16)(s & 511);
  }
}

// ---------------- bucket totals -> bucket edge offsets ----------------
__global__ void k_boff(const u32* __restrict__ gcntD, u32* __restrict__ bOffD){
  if(threadIdx.x==0){
    u32 run = 0;
    for(int i=0;i<NBUK;i++){ bOffD[i]=run; run+=gcntD[i]; }
  }
}

// ---------------- per-dst-bucket: degi, nd, rowp, CSR fill ----------------
__global__ __launch_bounds__(256) void k_bucket_dst(
    const u32* __restrict__ pairD, const u32* __restrict__ gcntD,
    const u32* __restrict__ bOffD, int* __restrict__ degi,
    float* __restrict__ nd, int* __restrict__ rowp, int* __restrict__ csr){
  __shared__ u32 hist[512], excl[512], fill[512], tsum[256];
  int t = threadIdx.x, b = blockIdx.x;
  int base = b << 9;
  hist[t] = 0; hist[t+256] = 0; fill[t] = 0; fill[t+256] = 0;
  __syncthreads();
  int nD = gcntD[b];
  const u32* pp = pairD + (size_t)b*CAP;
  for(int i=t; i<nD; i+=256) atomicAdd(&hist[pp[i] & 511], 1u);
  __syncthreads();
  // exclusive scan over 512 (2 per thread)
  u32 a0 = hist[2*t], a1 = hist[2*t+1];
  tsum[t] = a0 + a1;
  __syncthreads();
  for(int off=1; off<256; off<<=1){
    u32 v = (t>=off) ? tsum[t-off] : 0;
    __syncthreads();
    tsum[t] += v;
    __syncthreads();
  }
  u32 texc = tsum[t] - (a0 + a1);
  excl[2*t] = texc; excl[2*t+1] = texc + a0;
  __syncthreads();
  u32 bo = bOffD[b];
  #pragma unroll
  for(int j=0;j<2;j++){
    int local = t + j*256;
    int v = base + local;
    if(v < NN){
      int cnt = (int)hist[local];
      degi[v] = cnt + 1;                 // + self-loop
      nd[v] = rsqrtf((float)(cnt + 1));
      rowp[v] = (int)(bo + excl[local]);
    }
  }
  __syncthreads();
  for(int i=t; i<nD; i+=256){
    u32 w = pp[i];
    int local = w & 511;
    u32 pos = bo + excl[local] + atomicAdd(&fill[local], 1u);
    csr[pos] = (int)(w >> 9);
  }
}

// ---------------- per-src-bucket: ns ----------------
__global__ __launch_bounds__(256) void k_bucket_src(
    const u16* __restrict__ keyS, const u32* __restrict__ gcntS,
    float* __restrict__ ns){
  __shared__ u32 hist[512];
  int t = threadIdx.x, b = blockIdx.x;
  hist[t] = 0; hist[t+256] = 0;
  __syncthreads();
  int nS = gcntS[b];
  const u16* kp = keyS + (size_t)b*CAP;
  for(int i=t; i<nS; i+=256) atomicAdd(&hist[kp[i]], 1u);
  __syncthreads();
  #pragma unroll
  for(int j=0;j<2;j++){
    int local = t + j*256;
    int v = (b << 9) + local;
    if(v < NN) ns[v] = rsqrtf((float)(hist[local] + 1));
  }
}

// ---------------- convert features*ns -> bf16 ----------------
__global__ void k_cvt(const float* __restrict__ f, const float* __restrict__ ns,
                      u16* __restrict__ out){
  int i = blockIdx.x*256 + threadIdx.x;    // groups of 4 elems, 32 groups/row
  if(i >= NN*32) return;
  int row = i >> 5;
  float nsv = ns[row];
  float4 v = *(const float4*)(f + (size_t)i*4);
  u32 w0 = (u32)f2b(v.x*nsv) | ((u32)f2b(v.y*nsv) << 16);
  u32 w1 = (u32)f2b(v.z*nsv) | ((u32)f2b(v.w*nsv) << 16);
  *(uint2*)(out + (size_t)i*4) = make_uint2(w0, w1);
}

// ---------------- SpMM: 1 wave/node, EP edge-groups in parallel ----------------
template<int DIM, int EP>
__global__ void k_spmm_b(const u16* __restrict__ h, const int* __restrict__ rowp,
                         const int* __restrict__ degi, const int* __restrict__ csr,
                         const float* __restrict__ nd, u16* __restrict__ out){
  constexpr int G  = 64/EP;          // lanes per edge-group
  constexpr int NV = DIM/(G*8);      // uint4 (8 bf16) loads per lane
  int w = (blockIdx.x*blockDim.x + threadIdx.x) >> 6;
  int lane = threadIdx.x & 63;
  int g  = lane / G;
  int gl = lane % G;
  if(w >= NN) return;
  const uint4* hv = (const uint4*)h;       // DIM/8 uint4 per row
  float acc[NV*8];
  #pragma unroll
  for(int i=0;i<NV*8;i++) acc[i]=0.f;

  auto addrow = [&](int node){
    #pragma unroll
    for(int v4=0; v4<NV; v4++){
      uint4 v = hv[(size_t)node*(DIM/8) + gl*NV + v4];
      u32 wd[4] = {v.x, v.y, v.z, v.w};
      #pragma unroll
      for(int i=0;i<4;i++){
        acc[v4*8 + 2*i]   += b2f((u16)(wd[i] & 0xffff));
        acc[v4*8 + 2*i+1] += b2f((u16)(wd[i] >> 16));
      }
    }
  };

  if(g == 0) addrow(w);            // self-loop term
  int start = rowp[w];
  int cnt = degi[w]-1;
  for(int j=g; j<cnt; j+=EP) addrow(csr[start+j]);

  // combine edge-groups
  #pragma unroll
  for(int i=0;i<NV*8;i++){
    if(EP >= 8) acc[i] += __shfl_xor(acc[i], 8);
    if(EP >= 4) acc[i] += __shfl_xor(acc[i], 16);
    acc[i] += __shfl_xor(acc[i], 32);
  }
  if(g == 0){
    float ndv = nd[w];
    #pragma unroll
    for(int v4=0; v4<NV; v4++){
      u32 o[4];
      #pragma unroll
      for(int i=0;i<4;i++){
        o[i] = (u32)f2b(acc[v4*8+2*i]*ndv) | ((u32)f2b(acc[v4*8+2*i+1]*ndv) << 16);
      }
      *(uint4*)(out + (size_t)w*DIM + (gl*NV + v4)*8) = make_uint4(o[0],o[1],o[2],o[3]);
    }
  }
}

// ---------------- bf16 MFMA GEMM: out = relu(A @ Wt^T + bias) ----------------
// OUTMODE 0: bf16 out * ns[row]; 1: bf16 out; 2: fp32 out + BN col sums.
template<int OUTMODE>
__global__ __launch_bounds__(256) void k_gemm_mfma(
    const u16* __restrict__ A, const u16* __restrict__ Bt,
    const float* __restrict__ bias, const float* __restrict__ ns,
    u16* __restrict__ outb, float* __restrict__ outf,
    float* __restrict__ bns, float* __restrict__ bnq,
    int M, int K, int Nn)
{
  __shared__ u16 As[128*32];
  __shared__ u16 Bs[128*32];
  int t = threadIdx.x;
  int wave = t >> 6, lane = t & 63;
  int l15 = lane & 15, l4 = lane >> 4;
  int wr = (wave >> 1)*64, wc = (wave & 1)*64;
  int row0 = blockIdx.y*128, col0 = blockIdx.x*128;

  f32x4 acc[4][4];
  #pragma unroll
  for(int m=0;m<4;m++)
    #pragma unroll
    for(int n=0;n<4;n++) acc[m][n] = (f32x4)(0.f);

  int st_r = t >> 1;
  int kc0 = (t & 1)*2;
  int sw  = (st_r >> 1) & 3;
  int c0 = kc0 ^ sw, c1 = (kc0+1) ^ sw;
  bool avalid = (row0 + st_r) < M;
  bool bvalid = (col0 + st_r) < Nn;
  const u16* Ap = A  + (size_t)(row0 + st_r)*K + kc0*8;
  const u16* Bp = Bt + (size_t)(col0 + st_r)*K + kc0*8;

  for(int k0 = 0; k0 < K; k0 += 32){
    uint4 va0 = make_uint4(0,0,0,0), va1 = va0, vb0 = va0, vb1 = va0;
    if(avalid){ va0 = *(const uint4*)(Ap + k0); va1 = *(const uint4*)(Ap + k0 + 8); }
    if(bvalid){ vb0 = *(const uint4*)(Bp + k0); vb1 = *(const uint4*)(Bp + k0 + 8); }
    __syncthreads();
    *(uint4*)&As[st_r*32 + c0*8] = va0;
    *(uint4*)&As[st_r*32 + c1*8] = va1;
    *(uint4*)&Bs[st_r*32 + c0*8] = vb0;
    *(uint4*)&Bs[st_r*32 + c1*8] = vb1;
    __syncthreads();

    short8v af[4], bg[4];
    #pragma unroll
    for(int m=0;m<4;m++){
      int r = wr + m*16 + l15;
      int kc = l4 ^ ((r >> 1) & 3);
      af[m] = *(const short8v*)&As[r*32 + kc*8];
    }
    #pragma unroll
    for(int n=0;n<4;n++){
      int r = wc + n*16 + l15;
      int kc = l4 ^ ((r >> 1) & 3);
      bg[n] = *(const short8v*)&Bs[r*32 + kc*8];
    }
    #pragma unroll
    for(int m=0;m<4;m++)
      #pragma unroll
      for(int n=0;n<4;n++)
        acc[m][n] = __builtin_amdgcn_mfma_f32_16x16x32_bf16(af[m], bg[n], acc[m][n], 0, 0, 0);
    __syncthreads();
  }

  float nsv[4][4];
  if(OUTMODE == 0){
    #pragma unroll
    for(int m=0;m<4;m++)
      #pragma unroll
      for(int r=0;r<4;r++){
        int gr = row0 + wr + m*16 + l4*4 + r;
        nsv[m][r] = (gr < M) ? ns[gr] : 0.f;
      }
  }
  #pragma unroll
  for(int n=0;n<4;n++){
    int gc = col0 + wc + n*16 + l15;
    float bv = (gc < Nn) ? bias[gc] : 0.f;
    float s = 0.f, q = 0.f;
    #pragma unroll
    for(int m=0;m<4;m++){
      #pragma unroll
      for(int r=0;r<4;r++){
        int gr = row0 + wr + m*16 + l4*4 + r;
        bool ok = (gr < M) && (gc < Nn);
        float v = ok ? fmaxf(acc[m][n][r] + bv, 0.f) : 0.f;
        if(ok){
          if(OUTMODE == 0)      outb[(size_t)gr*Nn + gc] = f2b(v * nsv[m][r]);
          else if(OUTMODE == 1) outb[(size_t)gr*Nn + gc] = f2b(v);
          else                  outf[(size_t)gr*Nn + gc] = v;
        }
        if(OUTMODE == 2){ s += v; q += v*v; }
      }
    }
    if(OUTMODE == 2){
      s += __shfl_xor(s, 16); s += __shfl_xor(s, 32);
      q += __shfl_xor(q, 16); q += __shfl_xor(q, 32);
      if(l4 == 0 && gc < Nn){ atomicAdd(&bns[gc], s); atomicAdd(&bnq[gc], q); }
    }
  }
}

// ---------------- batchnorm finalize + fused final linear ----------------
__global__ void k_bn2(const float* __restrict__ bns, const float* __restrict__ bnq,
                      const float* __restrict__ gamma, const float* __restrict__ beta,
                      const float* __restrict__ Wm2, const float* __restrict__ bm2,
                      float* __restrict__ w2a, float* __restrict__ cc2){
  __shared__ float c0s[200];
  int t = threadIdx.x;
  if(t<200){
    float mu  = bns[t] * (1.0f/NN);
    float var = bnq[t] * (1.0f/NN) - mu*mu;
    float a   = rsqrtf(var + 1e-5f) * gamma[t];
    w2a[t*2+0] = a*Wm2[t*2+0];
    w2a[t*2+1] = a*Wm2[t*2+1];
    c0s[t] = beta[t] - mu*a;
  }
  __syncthreads();
  if(t<2){
    float cst = bm2[t];
    for(int k=0;k<200;k++) cst += c0s[k]*Wm2[k*2+t];
    cc2[t] = cst;
  }
}

__global__ void k_final(const float* __restrict__ z, const float* __restrict__ w2a,
                        const float* __restrict__ cc2, float* __restrict__ out){
  int lane = threadIdx.x & 63;
  int gw = (blockIdx.x*blockDim.x + threadIdx.x) >> 6;
  if(gw >= NN) return;
  const float* zr = z + (size_t)gw*200;
  float p0=0.f, p1=0.f;
  #pragma unroll
  for(int i=0;i<4;i++){
    int c = lane + i*64;
    if(c<200){ float x=zr[c]; p0 += x*w2a[c*2+0]; p1 += x*w2a[c*2+1]; }
  }
  for(int off=32; off>0; off>>=1){
    p0 += __shfl_down(p0, off);
    p1 += __shfl_down(p1, off);
  }
  if(lane==0){ out[gw*2+0] = p0 + cc2[0]; out[gw*2+1] = p1 + cc2[1]; }
}

// ---------------- launch ----------------
extern "C" void kernel_launch(void* const* d_in, const int* in_sizes, int n_in,
                              void* d_out, int out_size, void* d_ws, size_t ws_size,
                              hipStream_t stream) {
  const float* features = (const float*)d_in[0];
  const int*   src = (const int*)d_in[1];
  const int*   dst = (const int*)d_in[2];
  const float* W0  = (const float*)d_in[3];
  const float* b0  = (const float*)d_in[4];
  const float* W1  = (const float*)d_in[5];
  const float* b1  = (const float*)d_in[6];
  const float* W2  = (const float*)d_in[7];
  const float* b2  = (const float*)d_in[8];
  const float* Wm1 = (const float*)d_in[9];
  const float* bm1 = (const float*)d_in[10];
  const float* gamma = (const float*)d_in[11];
  const float* beta  = (const float*)d_in[12];
  const float* Wm2 = (const float*)d_in[13];
  const float* bm2 = (const float*)d_in[14];
  float* out = (float*)d_out;

  char* p = (char*)d_ws;
  auto alloc = [&](size_t bytes)->void*{
    void* r = (void*)p; p += (bytes + 255) & ~(size_t)255; return r;
  };
  u16*   X    = (u16*)alloc((size_t)NN*256*2);
  u16*   Y    = (u16*)alloc((size_t)NN*256*2);
  float* z    = (float*)alloc((size_t)NN*200*4);     // 80 MB, dead until MLP GEMM
  int*   csr  = (int*)alloc((size_t)NE*4);
  int*   rowp = (int*)alloc((size_t)NN*4);
  int*   degi = (int*)alloc((size_t)NN*4);
  float* ns   = (float*)alloc((size_t)NN*4);
  float* nd   = (float*)alloc((size_t)NN*4);
  u32*   gcntD = (u32*)alloc(256*4);
  u32*   gcntS = (u32*)alloc(256*4);
  u32*   bOffD = (u32*)alloc(256*4);
  float* bns  = (float*)alloc(200*4);
  float* bnq  = (float*)alloc(200*4);
  float* w2a  = (float*)alloc(400*4);
  float* cc2  = (float*)alloc(2*4);
  u16*   wt0  = (u16*)alloc((size_t)128*128*2);
  u16*   wt1  = (u16*)alloc((size_t)256*128*2);
  u16*   wt2  = (u16*)alloc((size_t)256*256*2);
  u16*   wtm1 = (u16*)alloc((size_t)200*256*2);
  // bucket scratch aliased onto z (lifetimes disjoint): pairD 14.5MB, keyS 7.3MB
  u32*   pairD = (u32*)z;
  u16*   keyS  = (u16*)((char*)z + (size_t)32*1024*1024);

  // prep: transposes + zero counters, then binned counting sort
  k_misc<<<(16384+32768+65536+51200+512+400 + 255)/256, 256, 0, stream>>>(
      W0, W1, W2, Wm1, wt0, wt1, wt2, wtm1, gcntD, gcntS, bns, bnq);
  k_bin<<<NAB, 256, 0, stream>>>(src, dst, gcntD, gcntS, pairD, keyS);
  k_boff<<<1, 64, 0, stream>>>(gcntD, bOffD);
  k_bucket_dst<<<NBUK, 256, 0, stream>>>(pairD, gcntD, bOffD, degi, nd, rowp, csr);
  k_bucket_src<<<NBUK, 256, 0, stream>>>(keyS, gcntS, ns);

  // features * ns -> bf16
  k_cvt<<<(NN*32 + 255)/256, 256, 0, stream>>>(features, ns, X);

  int sblk = (NN + 3)/4;           // 1 wave per node
  int gblk = (NN + 127)/128;       // GEMM row blocks

  // layer 0
  k_spmm_b<128,8><<<sblk, 256, 0, stream>>>(X, rowp, degi, csr, nd, Y);
  k_gemm_mfma<0><<<dim3(1,gblk), 256, 0, stream>>>(Y, wt0, b0, ns, X, nullptr, nullptr, nullptr, NN, 128, 128);
  // layer 1
  k_spmm_b<128,8><<<sblk, 256, 0, stream>>>(X, rowp, degi, csr, nd, Y);
  k_gemm_mfma<0><<<dim3(2,gblk), 256, 0, stream>>>(Y, wt1, b1, ns, X, nullptr, nullptr, nullptr, NN, 128, 256);
  // layer 2
  k_spmm_b<256,8><<<sblk, 256, 0, stream>>>(X, rowp, degi, csr, nd, Y);
  k_gemm_mfma<1><<<dim3(2,gblk), 256, 0, stream>>>(Y, wt2, b2, nullptr, X, nullptr, nullptr, nullptr, NN, 256, 256);
  // MLP hidden: z = relu(h3 @ Wm1 + bm1) + fused BN column stats
  k_gemm_mfma<2><<<dim3(2,gblk), 256, 0, stream>>>(X, wtm1, bm1, nullptr, nullptr, z, bns, bnq, NN, 256, 200);

  // batchnorm finalize + final linear
  k_bn2<<<1, 256, 0, stream>>>(bns, bnq, gamma, beta, Wm2, bm2, w2a, cc2);
  k_final<<<sblk, 256, 0, stream>>>(z, w2a, cc2, out);
}